// Round 1
// baseline (434.751 us; speedup 1.0000x reference)
//
#include <hip/hip_runtime.h>

typedef _Float16 half8_t __attribute__((ext_vector_type(8)));
typedef float f32x4 __attribute__((ext_vector_type(4)));

#define B_ 128
#define N_ 4096
#define H_ 128
#define P_ 128
#define CCH 16                       // chunks per batch row
#define ROWS_PER_CHUNK (N_ / CCH)    // 256
#define TILE 64
#define TILES (ROWS_PER_CHUNK / TILE) // 4

// workspace layout (float offsets)
#define OFF_SCALES 0          // [0]=sv [1]=sq [2]=sa
#define OFF_WA     16         // 128 floats: normalized wa
#define OFF_QPC    256        // B*P floats: q_proj + bq + bv
#define OFF_BPACK  16640      // 16384 f16 = 8192 float slots: MFMA-packed Wv^T
#define OFF_LOGITS 24832      // B*N floats
#define OFF_PART   549120     // B*CCH*132 floats: per-(b,chunk) m,l,o[128],pad2
#define OFF_FIN    819456     // [b]=m_b, [B_+b]=1/l_b
// total 819712 floats = ~3.3 MB

__device__ __forceinline__ float block_reduce_sum(float val, float* red, int tid) {
    red[tid] = val;
    __syncthreads();
    for (int s = 128; s > 0; s >>= 1) {
        if (tid < s) red[tid] += red[tid + s];
        __syncthreads();
    }
    float r = red[0];
    __syncthreads();
    return r;
}

// ---------- K0a: norms, scales, normalized wa, MFMA-packed Wv ----------
__global__ __launch_bounds__(256) void k0a_prep(
    const float* __restrict__ Wv, const float* __restrict__ gv,
    const float* __restrict__ Wq, const float* __restrict__ gq,
    const float* __restrict__ Wa, const float* __restrict__ ga,
    float* __restrict__ ws)
{
    __shared__ float red[256];
    __shared__ float s_sv, s_sa;
    const int tid = threadIdx.x;

    float sv2 = 0.f, sq2 = 0.f, sa2 = 0.f;
    for (int i = tid; i < P_ * H_; i += 256) {
        float x = Wv[i]; sv2 += x * x;
        float y = Wq[i]; sq2 += y * y;
    }
    if (tid < P_) { float z = Wa[tid]; sa2 = z * z; }

    float nv2 = block_reduce_sum(sv2, red, tid);
    float nq2 = block_reduce_sum(sq2, red, tid);
    float na2 = block_reduce_sum(sa2, red, tid);

    if (tid == 0) {
        float sv = gv[0] / sqrtf(nv2);
        float sq = gq[0] / sqrtf(nq2);
        float sa = ga[0] / sqrtf(na2);
        ws[OFF_SCALES + 0] = sv;
        ws[OFF_SCALES + 1] = sq;
        ws[OFF_SCALES + 2] = sa;
        s_sv = sv; s_sa = sa;
    }
    __syncthreads();

    const float sv = s_sv, sa = s_sa;
    // Bpack[s]: s = ((kk*8+pt)*64 + L)*8 + j  ->  Wv[p][h]*sv with
    // p = pt*16 + (L&15), h = kk*32 + (L>>4)*8 + j   (MFMA B-fragment order)
    _Float16* bp = (_Float16*)(ws + OFF_BPACK);
    for (int s = tid; s < 16384; s += 256) {
        int j  = s & 7;
        int L  = (s >> 3) & 63;
        int pt = (s >> 9) & 7;
        int kk = s >> 12;
        int p = pt * 16 + (L & 15);
        int h = kk * 32 + (L >> 4) * 8 + j;
        bp[s] = (_Float16)(Wv[p * H_ + h] * sv);
    }
    if (tid < P_) ws[OFF_WA + tid] = Wa[tid] * sa;
}

// ---------- K0b: q_proj[b][p] = sq*(q[b]·Wq[p]) + bq[p] + bv[p] ----------
__global__ __launch_bounds__(128) void k0b_qproj(
    const float* __restrict__ q, const float* __restrict__ Wq,
    const float* __restrict__ bq, const float* __restrict__ bv,
    float* __restrict__ ws)
{
    const int b = blockIdx.x, p = threadIdx.x;
    const float sq = ws[OFF_SCALES + 1];
    const float* qr = q + b * H_;
    const float* wr = Wq + p * H_;
    float acc = 0.f;
#pragma unroll 8
    for (int h = 0; h < H_; ++h) acc += qr[h] * wr[h];
    ws[OFF_QPC + b * P_ + p] = acc * sq + bq[p] + bv[p];
}

// ---------- K1: logits + online-softmax partials (one pass over v) ----------
__global__ __launch_bounds__(256) void k1_main(
    const float* __restrict__ v, const float* __restrict__ mask,
    const float* __restrict__ ba, float* __restrict__ ws)
{
    const int c = blockIdx.x;   // chunk
    const int b = blockIdx.y;   // batch
    const int tid = threadIdx.x;
    const int lane = tid & 63;
    const int w = tid >> 6;     // wave id 0..3

    __shared__ __align__(16) _Float16 Bl[16384];   // 32 KB packed B-frags
    __shared__ float qpcs[P_];
    __shared__ float was[P_];
    __shared__ float lgbuf[TILE];
    __shared__ float wbuf[TILE];
    __shared__ float sc[4];                        // m_run, l_run, alpha
    __shared__ float oredu[256 * 4];

    {
        const uint4* src = (const uint4*)(ws + OFF_BPACK);
        uint4* dst = (uint4*)Bl;
#pragma unroll
        for (int i = 0; i < 8; ++i) dst[tid + i * 256] = src[tid + i * 256];
        if (tid < P_) {
            qpcs[tid] = ws[OFF_QPC + b * P_ + tid];
            was[tid]  = ws[OFF_WA + tid];
        }
        if (tid == 0) { sc[0] = -1e30f; sc[1] = 0.f; sc[2] = 0.f; }
    }
    float o4[4] = {0.f, 0.f, 0.f, 0.f};
    const float ba0 = ba[0];
    __syncthreads();

    const int h4 = (tid & 31) * 4;  // owned h range (phase C)
    const int rs = tid >> 5;        // owned row-subset (phase C)

    for (int it = 0; it < TILES; ++it) {
        const int n0 = c * ROWS_PER_CHUNK + it * TILE;

        // ---- phase A: 16 rows per wave, v_proj via MFMA, logits ----
        const int arow = n0 + w * 16 + (lane & 15);
        const int colb = (lane >> 4) * 8;
        const float* vrow = v + ((size_t)b * N_ + arow) * H_;
        half8_t af[4];
#pragma unroll
        for (int kk = 0; kk < 4; ++kk) {
            const float4* p4 = (const float4*)(vrow + kk * 32 + colb);
            float4 f0 = p4[0], f1 = p4[1];
            half8_t a;
            a[0] = (_Float16)f0.x; a[1] = (_Float16)f0.y;
            a[2] = (_Float16)f0.z; a[3] = (_Float16)f0.w;
            a[4] = (_Float16)f1.x; a[5] = (_Float16)f1.y;
            a[6] = (_Float16)f1.z; a[7] = (_Float16)f1.w;
            af[kk] = a;
        }
        float lp[4] = {0.f, 0.f, 0.f, 0.f};
        const int pcol = lane & 15;
#pragma unroll
        for (int pt = 0; pt < 8; ++pt) {
            f32x4 acc = {0.f, 0.f, 0.f, 0.f};
#pragma unroll
            for (int kk = 0; kk < 4; ++kk) {
                half8_t bf = *(const half8_t*)&Bl[(((kk * 8 + pt) * 64) + lane) * 8];
                acc = __builtin_amdgcn_mfma_f32_16x16x32_f16(af[kk], bf, acc, 0, 0, 0);
            }
            const int p = pt * 16 + pcol;
            const float qv = qpcs[p];
            const float wv = was[p];
#pragma unroll
            for (int r = 0; r < 4; ++r)
                lp[r] += fmaxf(acc[r] + qv, 0.f) * wv;
        }
#pragma unroll
        for (int m = 1; m <= 8; m <<= 1) {
#pragma unroll
            for (int r = 0; r < 4; ++r)
                lp[r] += __shfl_xor(lp[r], m, 64);
        }
        if ((lane & 15) == 0) {
#pragma unroll
            for (int r = 0; r < 4; ++r)
                lgbuf[w * 16 + (lane >> 4) * 4 + r] = lp[r];
        }
        __syncthreads();

        // ---- phase B: wave 0 does online-softmax bookkeeping ----
        if (w == 0) {
            const int r = lane;
            const int n = n0 + r;
            float lg = lgbuf[r] + ba0 + (1.0f - mask[b * N_ + n]) * (-10000.0f);
            ws[OFF_LOGITS + (size_t)b * N_ + n] = lg;
            float mt = lg;
#pragma unroll
            for (int m = 1; m <= 32; m <<= 1) mt = fmaxf(mt, __shfl_xor(mt, m, 64));
            const float m_old = sc[0];
            const float m_new = fmaxf(m_old, mt);
            const float alpha = __expf(m_old - m_new);
            const float wr = __expf(lg - m_new);
            wbuf[r] = wr;
            float s = wr;
#pragma unroll
            for (int m = 1; m <= 32; m <<= 1) s += __shfl_xor(s, m, 64);
            if (lane == 0) {
                sc[1] = sc[1] * alpha + s;
                sc[0] = m_new;
                sc[2] = alpha;
            }
        }
        __syncthreads();

        // ---- phase C: o[h] accumulation (tile re-read hits L1) ----
        const float alpha = sc[2];
#pragma unroll
        for (int qq = 0; qq < 4; ++qq) o4[qq] *= alpha;
#pragma unroll
        for (int k = 0; k < 8; ++k) {
            const int r = rs * 8 + k;
            const float wr = wbuf[r];
            const float4 vv = *(const float4*)(v + ((size_t)b * N_ + n0 + r) * H_ + h4);
            o4[0] += wr * vv.x; o4[1] += wr * vv.y;
            o4[2] += wr * vv.z; o4[3] += wr * vv.w;
        }
    }

    __syncthreads();
#pragma unroll
    for (int qq = 0; qq < 4; ++qq) oredu[tid * 4 + qq] = o4[qq];
    __syncthreads();

    float* part = ws + OFF_PART + ((size_t)b * CCH + c) * 132;
    if (tid < 32) {
        float s0 = 0.f, s1 = 0.f, s2 = 0.f, s3 = 0.f;
#pragma unroll
        for (int g = 0; g < 8; ++g) {
            const int bi = (g * 32 + tid) * 4;
            s0 += oredu[bi]; s1 += oredu[bi + 1];
            s2 += oredu[bi + 2]; s3 += oredu[bi + 3];
        }
        const int h = tid * 4;
        part[2 + h] = s0; part[2 + h + 1] = s1;
        part[2 + h + 2] = s2; part[2 + h + 3] = s3;
    }
    if (tid == 0) { part[0] = sc[0]; part[1] = sc[1]; }
}

// ---------- K2a: combine chunk partials -> att, global m/l ----------
__global__ __launch_bounds__(128) void k2a_combine(
    float* __restrict__ ws, float* __restrict__ out)
{
    const int b = blockIdx.x, h = threadIdx.x;
    const float* part = ws + OFF_PART + (size_t)b * CCH * 132;
    float m = -1e30f;
#pragma unroll
    for (int c = 0; c < CCH; ++c) m = fmaxf(m, part[c * 132]);
    float l = 0.f, a = 0.f;
#pragma unroll
    for (int c = 0; c < CCH; ++c) {
        const float e = __expf(part[c * 132] - m);
        l += e * part[c * 132 + 1];
        a += e * part[c * 132 + 2 + h];
    }
    out[b * H_ + h] = a / l;
    if (h == 0) {
        ws[OFF_FIN + b] = m;
        ws[OFF_FIN + B_ + b] = 1.0f / l;
    }
}

// ---------- K2b: w[b,n] = exp(logit - m_b) / l_b ----------
__global__ __launch_bounds__(256) void k2b_weights(
    const float* __restrict__ ws, float* __restrict__ out)
{
    const int idx = blockIdx.x * 256 + threadIdx.x;  // < B_*N_
    const int b = idx >> 12;
    const float lg = ws[OFF_LOGITS + idx];
    out[B_ * H_ + idx] = __expf(lg - ws[OFF_FIN + b]) * ws[OFF_FIN + B_ + b];
}

extern "C" void kernel_launch(void* const* d_in, const int* in_sizes, int n_in,
                              void* d_out, int out_size, void* d_ws, size_t ws_size,
                              hipStream_t stream) {
    const float* v    = (const float*)d_in[0];
    const float* q    = (const float*)d_in[1];
    const float* mask = (const float*)d_in[2];
    const float* Wv   = (const float*)d_in[3];
    const float* bv   = (const float*)d_in[4];
    const float* gv   = (const float*)d_in[5];
    const float* Wq   = (const float*)d_in[6];
    const float* bq   = (const float*)d_in[7];
    const float* gq   = (const float*)d_in[8];
    const float* Wa   = (const float*)d_in[9];
    const float* ba   = (const float*)d_in[10];
    const float* ga   = (const float*)d_in[11];
    float* out = (float*)d_out;
    float* ws  = (float*)d_ws;

    k0a_prep<<<1, 256, 0, stream>>>(Wv, gv, Wq, gq, Wa, ga, ws);
    k0b_qproj<<<B_, 128, 0, stream>>>(q, Wq, bq, bv, ws);
    k1_main<<<dim3(CCH, B_), 256, 0, stream>>>(v, mask, ba, ws);
    k2a_combine<<<B_, 128, 0, stream>>>(ws, out);
    k2b_weights<<<(B_ * N_) / 256, 256, 0, stream>>>(ws, out);
}